// Round 1
// baseline (509.594 us; speedup 1.0000x reference)
//
#include <hip/hip_runtime.h>

// Row-wise Pearson correlation: N=262144 rows, D=256 cols, fp32 in/out.
// One wave (64 lanes) per row; lane i loads float4 at col 4*i -> 1KiB
// coalesced per row per input. Butterfly shfl_xor reduction of 5 moments.

#define D_COLS 256

__global__ __launch_bounds__(256, 8)
void pearson_rows_kernel(const float* __restrict__ v1,
                         const float* __restrict__ v2,
                         float* __restrict__ out,
                         int nrows) {
    const int lane         = threadIdx.x & 63;
    const int waveInBlock  = threadIdx.x >> 6;
    const int wavesPerBlk  = blockDim.x >> 6;
    const int globalWave   = blockIdx.x * wavesPerBlk + waveInBlock;
    const int totalWaves   = gridDim.x * wavesPerBlk;

    for (int row = globalWave; row < nrows; row += totalWaves) {
        const float4 a = reinterpret_cast<const float4*>(v1 + (size_t)row * D_COLS)[lane];
        const float4 b = reinterpret_cast<const float4*>(v2 + (size_t)row * D_COLS)[lane];

        float sx  = a.x + a.y + a.z + a.w;
        float sy  = b.x + b.y + b.z + b.w;
        float sxy = a.x * b.x + a.y * b.y + a.z * b.z + a.w * b.w;
        float sxx = a.x * a.x + a.y * a.y + a.z * a.z + a.w * a.w;
        float syy = b.x * b.x + b.y * b.y + b.z * b.z + b.w * b.w;

        // 64-lane butterfly reduction (6 steps x 5 values)
        #pragma unroll
        for (int off = 32; off >= 1; off >>= 1) {
            sx  += __shfl_xor(sx,  off, 64);
            sy  += __shfl_xor(sy,  off, 64);
            sxy += __shfl_xor(sxy, off, 64);
            sxx += __shfl_xor(sxx, off, 64);
            syy += __shfl_xor(syy, off, 64);
        }

        if (lane == 0) {
            const float d    = (float)D_COLS;
            const float Exy  = sxy / d;
            const float Ex   = sx  / d;
            const float Ey   = sy  / d;
            const float var1 = (sxx - sx * sx / d) / (d - 1.0f);
            const float var2 = (syy - sy * sy / d) / (d - 1.0f);
            out[row] = (Exy - Ex * Ey) / sqrtf(var1 * var2);
        }
    }
}

extern "C" void kernel_launch(void* const* d_in, const int* in_sizes, int n_in,
                              void* d_out, int out_size, void* d_ws, size_t ws_size,
                              hipStream_t stream) {
    const float* v1 = (const float*)d_in[0];
    const float* v2 = (const float*)d_in[1];
    float* out = (float*)d_out;

    const int nrows = in_sizes[0] / D_COLS;   // 262144

    const int block = 256;                    // 4 waves/block
    const int grid  = 2048;                   // 8192 waves, 32 rows each (grid-stride)
    pearson_rows_kernel<<<grid, block, 0, stream>>>(v1, v2, out, nrows);
}